// Round 7
// baseline (405.219 us; speedup 1.0000x reference)
//
#include <hip/hip_runtime.h>

// DiffeomorphicTransform: flow = velocity/2^7; 7x { grid = sample_grid + flow*rf;
// flow = flow + trilerp(flow, grid) }  (border clamp, align_corners=True)
//
// R7: merge the 3 channel-threads back into one thread per voxel. R6 showed
// the limiter is vmem issue/address throughput (FETCH collapsed to 21.7 MB,
// HBM 12%, dur barely moved): channel-split spent 24 vmem instr + 3x address
// math per voxel. Merged: 18 vmem instr (3 base + 12 pair-gathers sharing the
// same 4 row offsets across channels + 3 stores), weights computed once.
// Keeps R6's z-slab XCD swizzle + analytic identity grid + deferred scale.

constexpr int D = 128, H = 160, W = 128;
constexpr int N = D * H * W;             // 2,621,440 voxels
constexpr int VOX_BLOCKS = N / 256;      // 10240 blocks
constexpr int NUM_XCD = 8;
constexpr int CHUNKS_PER_XCD = VOX_BLOCKS / NUM_XCD;   // 1280

// 4-byte-aligned float pair (x-adjacent corners)
struct __attribute__((packed)) fpair { float lo, hi; };

__global__ __launch_bounds__(256)
void diffeo_step(const float* __restrict__ src,   // [3][N] flow (deferred scale)
                 const float* __restrict__ rf_p,  // scalar range_flow
                 float* __restrict__ dst,         // [3][N]
                 float scale)                     // 1/128 on step 1, else 1.0
{
    // z-slab XCD swizzle (R6-validated): XCD = blockIdx%8 owns a contiguous
    // 16-z-slice slab, walked sequentially (moving L2 window).
    const int b   = blockIdx.x;              // 0..10239
    const int xcd = b & (NUM_XCD - 1);
    const int k   = b >> 3;                  // 0..1279
    const int vb  = xcd * CHUNKS_PER_XCD + k;
    const int i   = vb * 256 + threadIdx.x;  // voxel id [0,N)

    const float rf = rf_p[0];

    // voxel coords (W=128 pow2)
    const int x = i & (W - 1);
    const int r = i >> 7;                    // z*H + y
    const int y = r % H;
    const int z = r / H;

    // flow at this voxel (deferred scale)
    const float fx = src[i]         * scale;
    const float fy = src[i + N]     * scale;
    const float fz = src[i + 2 * N] * scale;

    // analytic identity grid: unnormalized coord = x + flow*rf*0.5*(dim-1)
    const float ix = fminf(fmaxf((float)x + fx * (rf * 0.5f * (float)(W - 1)), 0.0f), (float)(W - 1));
    const float iy = fminf(fmaxf((float)y + fy * (rf * 0.5f * (float)(H - 1)), 0.0f), (float)(H - 1));
    const float iz = fminf(fmaxf((float)z + fz * (rf * 0.5f * (float)(D - 1)), 0.0f), (float)(D - 1));

    const float x0f = floorf(ix), y0f = floorf(iy), z0f = floorf(iz);
    const float wx = ix - x0f, wy = iy - y0f, wz = iz - z0f;
    const int x0 = (int)x0f, y0 = (int)y0f, z0 = (int)z0f;
    const int y1 = min(y0 + 1, H - 1);
    const int z1 = min(z0 + 1, D - 1);

    // pair-load base: when x0==W-1, wx==0 and x1==x0, so loading [W-2,W-1]
    // and selecting .hi for v0 is exact. Never reads outside the row.
    const int xb = min(x0, W - 2);
    const bool hix = (x0 == W - 1);

    // 4 row offsets, shared by all 3 channels (SGPR base differs only)
    int ofs[4];
    ofs[0] = (z0 * H + y0) * W + xb;
    ofs[1] = (z0 * H + y1) * W + xb;
    ofs[2] = (z1 * H + y0) * W + xb;
    ofs[3] = (z1 * H + y1) * W + xb;

    // 12 independent 8B gathers — one vmcnt batch, then compute
    fpair p[3][4];
#pragma unroll
    for (int c = 0; c < 3; ++c) {
        const float* __restrict__ s = src + c * N;
#pragma unroll
        for (int q = 0; q < 4; ++q)
            p[c][q] = *(const fpair*)(s + ofs[q]);
    }

    const float omx = 1.0f - wx, omy = 1.0f - wy, omz = 1.0f - wz;
    const float fbase[3] = {fx, fy, fz};

#pragma unroll
    for (int c = 0; c < 3; ++c) {
        const float v00 = hix ? p[c][0].hi : p[c][0].lo;   // z0,y0
        const float v01 = hix ? p[c][1].hi : p[c][1].lo;   // z0,y1
        const float v10 = hix ? p[c][2].hi : p[c][2].lo;   // z1,y0
        const float v11 = hix ? p[c][3].hi : p[c][3].lo;   // z1,y1
        const float v = omz * (omy * (omx * v00 + wx * p[c][0].hi)
                             + wy  * (omx * v01 + wx * p[c][1].hi))
                      + wz  * (omy * (omx * v10 + wx * p[c][2].hi)
                             + wy  * (omx * v11 + wx * p[c][3].hi));
        dst[c * N + i] = fbase[c] + v * scale;   // deferred scale (trilerp linear)
    }
}

extern "C" void kernel_launch(void* const* d_in, const int* in_sizes, int n_in,
                              void* d_out, int out_size, void* d_ws, size_t ws_size,
                              hipStream_t stream)
{
    const float* vel = (const float*)d_in[0];   // [1,3,128,160,128]
    const float* rf  = (const float*)d_in[2];   // scalar range_flow
    float* out = (float*)d_out;                 // [1,3,128,160,128]
    float* ws  = (float*)d_ws;                  // needs 3*N*4 = 31.5 MB

    const dim3 blk(256);
    const dim3 grd(VOX_BLOCKS);                 // 10240 blocks

    // step 1: velocity (deferred /128) -> out
    diffeo_step<<<grd, blk, 0, stream>>>(vel, rf, out, 1.0f / 128.0f);
    // steps 2..7 ping-pong: out->ws, ws->out, ... ; step 7 ends in d_out
    float* bufs[2] = {out, ws};
    for (int it = 2; it <= 7; ++it) {
        float* s = bufs[it & 1];
        float* d = bufs[(it + 1) & 1];
        diffeo_step<<<grd, blk, 0, stream>>>(s, rf, d, 1.0f);
    }
}

// Round 8
// 375.554 us; speedup vs baseline: 1.0790x; 1.0790x over previous
//
#include <hip/hip_runtime.h>

// DiffeomorphicTransform: flow = velocity/2^7; 7x { grid = sample_grid + flow*rf;
// flow = flow + trilerp(flow, grid) }  (border clamp, align_corners=True)
//
// R8 = R6 (channel-split, pair-gathers, analytic grid, z-slab XCD swizzle)
// with 2 x-adjacent voxels per thread. R4-R7 ablation: at fixed traffic, dur
// tracks wave TLP and vmem instruction count; R7 (merged channels) serialized
// at VGPR=20. Here: 3 float2 base loads + 8 pair-gathers (one batch, ~40 VGPR
// live) + 1 float2 store = 12 vmem/thread vs R6's 8 for half the work
// (-25% instr/CU at equal in-flight gathers 240x8 == 480x4).

constexpr int D = 128, H = 160, W = 128;
constexpr int N = D * H * W;               // 2,621,440 voxels
constexpr int PAIRS = N / 2;               // 1,310,720 x-pairs
constexpr int PAIR_BLOCKS = PAIRS / 256;   // 5120 pair-chunks (512 voxels each)
constexpr int NUM_XCD = 8;
constexpr int CHUNKS_PER_XCD = PAIR_BLOCKS / NUM_XCD;   // 640

// 4-byte-aligned float pair (x-adjacent corners)
struct __attribute__((packed)) fpair { float lo, hi; };

__global__ __launch_bounds__(256)
void diffeo_step(const float* __restrict__ src,   // [3][N] flow (deferred scale)
                 const float* __restrict__ rf_p,  // scalar range_flow
                 float* __restrict__ dst,         // [3][N]
                 float scale)                     // 1/128 on step 1, else 1.0
{
    // z-slab XCD swizzle (R6-validated): XCD = blockIdx%8 owns a contiguous
    // 16-z-slice slab; per-XCD order walks it sequentially, 3 channels of a
    // chunk back-to-back.
    const int b   = blockIdx.x;              // 0..15359
    const int xcd = b & (NUM_XCD - 1);
    const int k   = b >> 3;                  // 0..1919
    const int bc  = k % 3;                   // channel (block-uniform)
    const int s_  = k / 3;                   // slab-local chunk 0..639
    const int pb  = xcd * CHUNKS_PER_XCD + s_;   // pair-chunk 0..5119
    const int t   = pb * 256 + threadIdx.x;      // pair id [0, PAIRS)
    const int i0  = 2 * t;                       // first voxel (even x, same row)

    const float rf = rf_p[0];

    // voxel coords (W=128 pow2; pair never crosses a row)
    const int x = i0 & (W - 1);
    const int r = i0 >> 7;                   // z*H + y
    const int y = r % H;
    const int z = r / H;

    // coalesced float2 base loads, all 3 components for both voxels
    const float2 f0 = ((const float2*)(src))[t];
    const float2 f1 = ((const float2*)(src + N))[t];
    const float2 f2 = ((const float2*)(src + 2 * N))[t];

    const float sxw = rf * 0.5f * (float)(W - 1);
    const float syw = rf * 0.5f * (float)(H - 1);
    const float szw = rf * 0.5f * (float)(D - 1);

    float wxa[2], wya[2], wza[2], fca[2];
    int   ofs[2][4];
    bool  hix[2];

#pragma unroll
    for (int j = 0; j < 2; ++j) {
        const float fx = (j ? f0.y : f0.x) * scale;
        const float fy = (j ? f1.y : f1.x) * scale;
        const float fz = (j ? f2.y : f2.x) * scale;
        fca[j] = (bc == 0) ? fx : (bc == 1) ? fy : fz;

        const float ix = fminf(fmaxf((float)(x + j) + fx * sxw, 0.0f), (float)(W - 1));
        const float iy = fminf(fmaxf((float)y       + fy * syw, 0.0f), (float)(H - 1));
        const float iz = fminf(fmaxf((float)z       + fz * szw, 0.0f), (float)(D - 1));

        const float x0f = floorf(ix), y0f = floorf(iy), z0f = floorf(iz);
        wxa[j] = ix - x0f; wya[j] = iy - y0f; wza[j] = iz - z0f;
        const int x0 = (int)x0f, y0 = (int)y0f, z0 = (int)z0f;
        const int y1 = min(y0 + 1, H - 1);
        const int z1 = min(z0 + 1, D - 1);

        // pair-load base: x0==W-1 implies wx==0 (x1==x0), select .hi — exact.
        const int xb = min(x0, W - 2);
        hix[j] = (x0 == W - 1);

        ofs[j][0] = (z0 * H + y0) * W + xb;
        ofs[j][1] = (z0 * H + y1) * W + xb;
        ofs[j][2] = (z1 * H + y0) * W + xb;
        ofs[j][3] = (z1 * H + y1) * W + xb;
    }

    // 8 independent 8B gathers — single vmcnt batch
    const float* __restrict__ s = src + bc * N;
    fpair p[2][4];
#pragma unroll
    for (int j = 0; j < 2; ++j)
#pragma unroll
        for (int q = 0; q < 4; ++q)
            p[j][q] = *(const fpair*)(s + ofs[j][q]);

    float outv[2];
#pragma unroll
    for (int j = 0; j < 2; ++j) {
        const float wx = wxa[j], wy = wya[j], wz = wza[j];
        const float omx = 1.0f - wx, omy = 1.0f - wy, omz = 1.0f - wz;
        const float v00 = hix[j] ? p[j][0].hi : p[j][0].lo;
        const float v01 = hix[j] ? p[j][1].hi : p[j][1].lo;
        const float v10 = hix[j] ? p[j][2].hi : p[j][2].lo;
        const float v11 = hix[j] ? p[j][3].hi : p[j][3].lo;
        const float v = omz * (omy * (omx * v00 + wx * p[j][0].hi)
                             + wy  * (omx * v01 + wx * p[j][1].hi))
                      + wz  * (omy * (omx * v10 + wx * p[j][2].hi)
                             + wy  * (omx * v11 + wx * p[j][3].hi));
        outv[j] = fca[j] + v * scale;    // deferred scale (trilerp linear)
    }

    ((float2*)(dst + bc * N))[t] = make_float2(outv[0], outv[1]);
}

extern "C" void kernel_launch(void* const* d_in, const int* in_sizes, int n_in,
                              void* d_out, int out_size, void* d_ws, size_t ws_size,
                              hipStream_t stream)
{
    const float* vel = (const float*)d_in[0];   // [1,3,128,160,128]
    const float* rf  = (const float*)d_in[2];   // scalar range_flow
    float* out = (float*)d_out;                 // [1,3,128,160,128]
    float* ws  = (float*)d_ws;                  // needs 3*N*4 = 31.5 MB

    const dim3 blk(256);
    const dim3 grd(3 * PAIR_BLOCKS);            // 15360 blocks

    // step 1: velocity (deferred /128) -> out
    diffeo_step<<<grd, blk, 0, stream>>>(vel, rf, out, 1.0f / 128.0f);
    // steps 2..7 ping-pong: out->ws, ws->out, ... ; step 7 ends in d_out
    float* bufs[2] = {out, ws};
    for (int it = 2; it <= 7; ++it) {
        float* s = bufs[it & 1];
        float* d = bufs[(it + 1) & 1];
        diffeo_step<<<grd, blk, 0, stream>>>(s, rf, d, 1.0f);
    }
}